// Round 16
// baseline (714.637 us; speedup 1.0000x reference)
//
#include <hip/hip_runtime.h>
#include <cmath>
#include <cstddef>

#define N_NODES 50000
#define N_PAD   50048
#define E_EDGES 640000
#define HDIM 128
#define COUT 64
#define NLAYERS 16
#define ALPHA_C 0.1f
#define LAMDA_C 0.5f
#define SCAN_BLKS 196   // ceil(50000/256)

typedef __attribute__((ext_vector_type(8))) short short8;
typedef __attribute__((ext_vector_type(4))) float f32x4;
typedef __attribute__((ext_vector_type(2))) float f32x2;
typedef __attribute__((address_space(1))) const unsigned int g_u32;
typedef __attribute__((address_space(3))) unsigned int l_u32;

__device__ __forceinline__ float bf2f(ushort u) {
    union { unsigned u; float f; } x; x.u = ((unsigned)u) << 16; return x.f;
}
__device__ __forceinline__ ushort f2bf(float f) {
    union { float f; unsigned u; } x; x.f = f;
    unsigned r = x.u + 0x7FFFu + ((x.u >> 16) & 1u);
    return (ushort)(r >> 16);
}

// ---------------- graph setup ----------------

__global__ __launch_bounds__(256) void k_init(float* deg, int* cnt) {
    int i = blockIdx.x * 256 + threadIdx.x;
    if (i < N_NODES) { deg[i] = 1.0f; cnt[i] = 0; }
}

// 4 edges/thread; cnt atomicAdd return value = intra-bucket rank (kills scatter atomics)
__global__ __launch_bounds__(256) void k_edge(const int* __restrict__ ei,
                                              const float* __restrict__ ew,
                                              float* deg, int* cnt,
                                              int* __restrict__ rank) {
    int t = blockIdx.x * 256 + threadIdx.x;
    int e0 = t * 4;
    if (e0 >= E_EDGES) return;
    int4 r = *(const int4*)&ei[e0];
    int4 c = *(const int4*)&ei[E_EDGES + e0];
    float4 w = *(const float4*)&ew[e0];
    atomicAdd(&deg[r.x], w.x);
    atomicAdd(&deg[r.y], w.y);
    atomicAdd(&deg[r.z], w.z);
    atomicAdd(&deg[r.w], w.w);
    int4 rk;
    rk.x = atomicAdd(&cnt[c.x], 1);
    rk.y = atomicAdd(&cnt[c.y], 1);
    rk.z = atomicAdd(&cnt[c.z], 1);
    rk.w = atomicAdd(&cnt[c.w], 1);
    *(int4*)&rank[e0] = rk;
}

__global__ __launch_bounds__(256) void k_dinv(float* deg) {
    int i = blockIdx.x * 256 + threadIdx.x;
    if (i < N_NODES) deg[i] = 1.0f / sqrtf(deg[i]);
}

__global__ __launch_bounds__(256) void k_scan1(const int* __restrict__ cnt,
                                               int* ptrTmp, int* bsum) {
    __shared__ int s[256];
    int t = threadIdx.x;
    int i = blockIdx.x * 256 + t;
    int v = (i < N_NODES) ? cnt[i] : 0;
    s[t] = v; __syncthreads();
    for (int off = 1; off < 256; off <<= 1) {
        int x = s[t]; int y = (t >= off) ? s[t - off] : 0;
        __syncthreads();
        s[t] = x + y; __syncthreads();
    }
    if (i < N_NODES) ptrTmp[i] = s[t] - v;
    if (t == 255) bsum[blockIdx.x] = s[255];
}

__global__ __launch_bounds__(256) void k_scan2(const int* __restrict__ bsum, int* boff) {
    __shared__ int s[256];
    int t = threadIdx.x;
    int v = (t < SCAN_BLKS) ? bsum[t] : 0;
    s[t] = v; __syncthreads();
    for (int off = 1; off < 256; off <<= 1) {
        int x = s[t]; int y = (t >= off) ? s[t - off] : 0;
        __syncthreads();
        s[t] = x + y; __syncthreads();
    }
    if (t < SCAN_BLKS) boff[t] = s[t] - v;
}

__global__ __launch_bounds__(256) void k_scan3(const int* __restrict__ ptrTmp,
                                               const int* __restrict__ boff, int* ptr) {
    int i = blockIdx.x * 256 + threadIdx.x;
    if (i < N_NODES) ptr[i] = ptrTmp[i] + boff[blockIdx.x];
    if (i == 0) ptr[N_NODES] = E_EDGES;
}

// atomic-free scatter: pos = ptr[c] + rank[e]; meta packed (row<<16 | bf16(norm))
__global__ __launch_bounds__(256) void k_scatter(const int* __restrict__ ei,
                                                 const float* __restrict__ ew,
                                                 const float* __restrict__ dinv,
                                                 const int* __restrict__ ptr,
                                                 const int* __restrict__ rank,
                                                 unsigned* __restrict__ spacku) {
    int t = blockIdx.x * 256 + threadIdx.x;
    int e0 = t * 4;
    if (e0 >= E_EDGES) return;
    int4 r = *(const int4*)&ei[e0];
    int4 c = *(const int4*)&ei[E_EDGES + e0];
    float4 w = *(const float4*)&ew[e0];
    int4 rk = *(const int4*)&rank[e0];
#pragma unroll
    for (int j = 0; j < 4; ++j) {
        int rr = (j == 0) ? r.x : (j == 1) ? r.y : (j == 2) ? r.z : r.w;
        int cc = (j == 0) ? c.x : (j == 1) ? c.y : (j == 2) ? c.z : c.w;
        float wwv = (j == 0) ? w.x : (j == 1) ? w.y : (j == 2) ? w.z : w.w;
        int rkj = (j == 0) ? rk.x : (j == 1) ? rk.y : (j == 2) ? rk.z : rk.w;
        int pos = ptr[cc] + rkj;
        float nm = dinv[rr] * wwv * dinv[cc];
        spacku[pos] = ((unsigned)rr << 16) | (unsigned)f2bf(nm);
    }
}

// ---------------- weight convert + transpose + residual fold ----------------
// layer weights become W' = beta*W + diagC*I, stored bf16 transposed [C][R]

__global__ __launch_bounds__(256) void k_convert_w(
    const float* __restrict__ w_in, const float* __restrict__ ws1,
    const float* __restrict__ ws2, const float* __restrict__ w_out,
    ushort* wt_in, ushort* wt1, ushort* wt2, ushort* wt_out) {
    __shared__ float tile[128][129];
    int b = blockIdx.x;
    const float* src; ushort* dst; int R = 128, C = 128;
    float scale = 1.f, diag = 0.f;
    if (b == 0) { src = w_in; dst = wt_in; }
    else if (b <= 16) {
        int i = b - 1;
        float beta = logf(LAMDA_C / (float)(i + 1) + 1.0f);
        scale = beta; diag = (1.f - beta) * (1.f - ALPHA_C);
        src = ws1 + (size_t)i * 16384; dst = wt1 + (size_t)i * 16384;
    } else if (b <= 32) {
        int i = b - 17;
        float beta = logf(LAMDA_C / (float)(i + 1) + 1.0f);
        scale = beta; diag = (1.f - beta) * ALPHA_C;
        src = ws2 + (size_t)i * 16384; dst = wt2 + (size_t)i * 16384;
    } else { src = w_out; dst = wt_out; C = 64; }
    for (int idx = threadIdx.x; idx < R * C; idx += 256) {
        int k = idx / C, n = idx % C;
        tile[k][n] = src[idx] * scale + ((k == n) ? diag : 0.f);
    }
    __syncthreads();
    for (int idx = threadIdx.x; idx < R * C; idx += 256) {
        int n = idx / R, k = idx % R;
        dst[idx] = f2bf(tile[k][n]);
    }
}

// ---------------- x convert (f32 -> bf16, zero-pad rows) ----------------

__global__ __launch_bounds__(256) void k_convert_x(const float* __restrict__ x,
                                                   ushort* __restrict__ xb) {
    int c8 = blockIdx.x * 256 + threadIdx.x;
    if (c8 >= N_PAD * (HDIM / 8)) return;
    int row = c8 / (HDIM / 8);
    short8 o;
    if (row < N_NODES) {
        const float4 f0 = *(const float4*)&x[(size_t)c8 * 8];
        const float4 f1 = *(const float4*)&x[(size_t)c8 * 8 + 4];
        o[0] = (short)f2bf(f0.x); o[1] = (short)f2bf(f0.y);
        o[2] = (short)f2bf(f0.z); o[3] = (short)f2bf(f0.w);
        o[4] = (short)f2bf(f1.x); o[5] = (short)f2bf(f1.y);
        o[6] = (short)f2bf(f1.z); o[7] = (short)f2bf(f1.w);
    } else {
        o = (short8){0, 0, 0, 0, 0, 0, 0, 0};
    }
    *(short8*)&xb[(size_t)c8 * 8] = o;
}

// ---------------- input GEMM: h0 = relu(xb @ W + bias); also h8 (fp8 perm) ----------------
// h8 byte pdim=(dim&15)*8+(dim>>4).

__global__ __launch_bounds__(256) void k_gemm_in(
    const ushort* __restrict__ A, const ushort* __restrict__ W,
    const float* __restrict__ bias, ushort* __restrict__ H0,
    unsigned char* __restrict__ H8) {
    const int tid = threadIdx.x;
    const int wid = tid >> 6, l = tid & 63;
    const int wm = wid >> 1, wn = wid & 1;
    const int lr = l & 15, lk = l >> 4;
    const int row0 = blockIdx.x * 128 + wm * 64;
    const int col0 = wn * 64;

    short8 a[4][4], b[4][4];
#pragma unroll
    for (int m = 0; m < 4; ++m)
#pragma unroll
        for (int k = 0; k < 4; ++k)
            a[m][k] = *(const short8*)&A[(size_t)(row0 + m * 16 + lr) * HDIM + k * 32 + lk * 8];
#pragma unroll
    for (int n = 0; n < 4; ++n)
#pragma unroll
        for (int k = 0; k < 4; ++k)
            b[n][k] = *(const short8*)&W[(size_t)(col0 + n * 16 + lr) * HDIM + k * 32 + lk * 8];

    f32x4 acc[4][4];
#pragma unroll
    for (int m = 0; m < 4; ++m)
#pragma unroll
        for (int n = 0; n < 4; ++n) acc[m][n] = (f32x4){0.f, 0.f, 0.f, 0.f};
#pragma unroll
    for (int k = 0; k < 4; ++k)
#pragma unroll
        for (int m = 0; m < 4; ++m)
#pragma unroll
            for (int n = 0; n < 4; ++n)
                acc[m][n] = __builtin_amdgcn_mfma_f32_16x16x32_bf16(a[m][k], b[n][k], acc[m][n], 0, 0, 0);

    float bv[4];
#pragma unroll
    for (int n = 0; n < 4; ++n) bv[n] = bias[col0 + n * 16 + lr];
#pragma unroll
    for (int m = 0; m < 4; ++m) {
        const int rb = row0 + m * 16 + lk * 4;
#pragma unroll
        for (int j = 0; j < 4; ++j) {
            const int row = rb + j;
            const size_t ro = (size_t)row * HDIM;
            float v[4];
#pragma unroll
            for (int n = 0; n < 4; ++n) {
                v[n] = fmaxf(acc[m][n][j] + bv[n], 0.f);
                H0[ro + col0 + n * 16 + lr] = f2bf(v[n]);
            }
            unsigned pk = 0;
            pk = __builtin_amdgcn_cvt_pk_fp8_f32(v[0], v[1], pk, false);
            pk = __builtin_amdgcn_cvt_pk_fp8_f32(v[2], v[3], pk, true);
            *(unsigned*)&H8[(size_t)row * HDIM + lr * 8 + wn * 4] = pk;
        }
    }
}

// ---------------- aggregation: agg_h = A_hat * h  (fp8 gathers, 128B/edge) ----------------
// R13 shape: wave per node; quarter-wave (16 lanes x uint2 = 128B row) per edge;
// 16 edges in flight (4x unroll); branch-free (padded lanes carry meta=0).

__global__ __launch_bounds__(256) void k_aggregate(
    const unsigned char* __restrict__ h8, const float* __restrict__ dinv,
    const int* __restrict__ ptr, const unsigned* __restrict__ spacku,
    ushort* __restrict__ agg_h) {
    const int v = blockIdx.x * 4 + (threadIdx.x >> 6);
    const int l = threadIdx.x & 63;
    const int q = l >> 4, i = l & 15;
    if (v >= N_NODES) return;
    const int beg = ptr[v], end = ptr[v + 1];

    float acc[8];
#pragma unroll
    for (int d = 0; d < 8; ++d) acc[d] = 0.f;

    for (int base = beg; base < end; base += 64) {
        const int cnt = min(64, end - base);
        unsigned meta = 0;
        if (base + l < end) meta = spacku[base + l];
        for (int j = 0; j < cnt; j += 16) {
            unsigned mu0 = (unsigned)__shfl((int)meta, j + q);
            unsigned mu1 = (unsigned)__shfl((int)meta, j + 4 + q);
            unsigned mu2 = (unsigned)__shfl((int)meta, j + 8 + q);
            unsigned mu3 = (unsigned)__shfl((int)meta, j + 12 + q);
            uint2 u0 = *(const uint2*)&h8[(size_t)(mu0 >> 16) * HDIM + i * 8];
            uint2 u1 = *(const uint2*)&h8[(size_t)(mu1 >> 16) * HDIM + i * 8];
            uint2 u2 = *(const uint2*)&h8[(size_t)(mu2 >> 16) * HDIM + i * 8];
            uint2 u3 = *(const uint2*)&h8[(size_t)(mu3 >> 16) * HDIM + i * 8];
            float nn0 = bf2f((ushort)(mu0 & 0xFFFFu));
            float nn1 = bf2f((ushort)(mu1 & 0xFFFFu));
            float nn2 = bf2f((ushort)(mu2 & 0xFFFFu));
            float nn3 = bf2f((ushort)(mu3 & 0xFFFFu));
#pragma unroll
            for (int e = 0; e < 4; ++e) {
                uint2 u = (e == 0) ? u0 : (e == 1) ? u1 : (e == 2) ? u2 : u3;
                float nn = (e == 0) ? nn0 : (e == 1) ? nn1 : (e == 2) ? nn2 : nn3;
                f32x2 f0 = __builtin_amdgcn_cvt_pk_f32_fp8(u.x, false);
                f32x2 f1 = __builtin_amdgcn_cvt_pk_f32_fp8(u.x, true);
                f32x2 f2 = __builtin_amdgcn_cvt_pk_f32_fp8(u.y, false);
                f32x2 f3 = __builtin_amdgcn_cvt_pk_f32_fp8(u.y, true);
                acc[0] = fmaf(nn, f0.x, acc[0]);
                acc[1] = fmaf(nn, f0.y, acc[1]);
                acc[2] = fmaf(nn, f1.x, acc[2]);
                acc[3] = fmaf(nn, f1.y, acc[3]);
                acc[4] = fmaf(nn, f2.x, acc[4]);
                acc[5] = fmaf(nn, f2.y, acc[5]);
                acc[6] = fmaf(nn, f3.x, acc[6]);
                acc[7] = fmaf(nn, f3.y, acc[7]);
            }
        }
    }
#pragma unroll
    for (int d = 0; d < 8; ++d) {
        acc[d] += __shfl_xor(acc[d], 16);
        acc[d] += __shfl_xor(acc[d], 32);
    }
    if (q == 0) {
        const float dv = dinv[v];
        const float dv2 = dv * dv;
        uint2 u = *(const uint2*)&h8[(size_t)v * HDIM + i * 8];
        f32x2 f0 = __builtin_amdgcn_cvt_pk_f32_fp8(u.x, false);
        f32x2 f1 = __builtin_amdgcn_cvt_pk_f32_fp8(u.x, true);
        f32x2 f2 = __builtin_amdgcn_cvt_pk_f32_fp8(u.y, false);
        f32x2 f3 = __builtin_amdgcn_cvt_pk_f32_fp8(u.y, true);
        float s[8] = {f0.x, f0.y, f1.x, f1.y, f2.x, f2.y, f3.x, f3.y};
#pragma unroll
        for (int n = 0; n < 8; ++n)
            agg_h[(size_t)v * HDIM + n * 16 + i] = f2bf(acc[n] + dv2 * s[n]);
    }
}

// ---------------- layer GEMM: h = relu(agg_h @ W1' + h0 @ W2') ----------------
// Both A-tiles staged into 64KB LDS upfront (16 global_load_lds in flight),
// ONE barrier, then both K-phases from LDS. XOR-swizzled source (g^(row&7))
// keeps linear LDS + swizzled ds_read_b128 conflict-free.
// LAST=false: write only H8 (fp8). LAST=true (layer 15): write only H (bf16).

template <bool LAST>
__global__ __launch_bounds__(256, 2) void k_gemm_layer(
    const ushort* __restrict__ AGG, const ushort* __restrict__ H0,
    const ushort* __restrict__ W1, const ushort* __restrict__ W2,
    ushort* __restrict__ H, unsigned char* __restrict__ H8) {
    __shared__ ushort ldsA[2][128 * 128];   // 64 KB
    const int tid = threadIdx.x;
    const int wid = tid >> 6, l = tid & 63;
    const int wm = wid >> 1, wn = wid & 1;
    const int lr = l & 15, lk = l >> 4;
    const int tilebase = blockIdx.x * 128;
    const int col0 = wn * 64;

    f32x4 acc[4][4];
#pragma unroll
    for (int m = 0; m < 4; ++m)
#pragma unroll
        for (int n = 0; n < 4; ++n) acc[m][n] = (f32x4){0.f, 0.f, 0.f, 0.f};

    // stage BOTH 128x128 bf16 tiles (8 rounds x 4 waves x 64 lanes x 16B each)
#pragma unroll
    for (int ph = 0; ph < 2; ++ph) {
        const ushort* __restrict__ A = ph ? H0 : AGG;
#pragma unroll
        for (int r = 0; r < 8; ++r) {
            int p = (r * 4 + wid) * 64 + l;       // granule 0..2047
            int row = p >> 4, g = p & 15;
            int gs = g ^ (row & 7);
            __builtin_amdgcn_global_load_lds(
                (g_u32*)(A + (size_t)(tilebase + row) * HDIM + gs * 8),
                (l_u32*)&ldsA[ph][(size_t)p * 8], 16, 0, 0);
        }
    }
    __syncthreads();

#pragma unroll
    for (int ph = 0; ph < 2; ++ph) {
        const ushort* __restrict__ W = ph ? W2 : W1;
#pragma unroll
        for (int k = 0; k < 4; ++k) {
            short8 a[4], b[4];
#pragma unroll
            for (int m = 0; m < 4; ++m) {
                int rloc = wm * 64 + m * 16 + lr;
                int gs = (k * 4 + lk) ^ (rloc & 7);
                a[m] = *(const short8*)&ldsA[ph][rloc * 128 + gs * 8];
            }
#pragma unroll
            for (int n = 0; n < 4; ++n)
                b[n] = *(const short8*)&W[(size_t)(col0 + n * 16 + lr) * HDIM + k * 32 + lk * 8];
#pragma unroll
            for (int m = 0; m < 4; ++m)
#pragma unroll
                for (int n = 0; n < 4; ++n)
                    acc[m][n] = __builtin_amdgcn_mfma_f32_16x16x32_bf16(a[m], b[n], acc[m][n], 0, 0, 0);
        }
    }

#pragma unroll
    for (int m = 0; m < 4; ++m) {
        const int rb = tilebase + wm * 64 + m * 16 + lk * 4;
#pragma unroll
        for (int j = 0; j < 4; ++j) {
            const int row = rb + j;
            const size_t ro = (size_t)row * HDIM;
            float v[4];
#pragma unroll
            for (int n = 0; n < 4; ++n) v[n] = fmaxf(acc[m][n][j], 0.f);
            if constexpr (LAST) {
#pragma unroll
                for (int n = 0; n < 4; ++n)
                    H[ro + col0 + n * 16 + lr] = f2bf(v[n]);
            } else {
                unsigned pk = 0;
                pk = __builtin_amdgcn_cvt_pk_fp8_f32(v[0], v[1], pk, false);
                pk = __builtin_amdgcn_cvt_pk_fp8_f32(v[2], v[3], pk, true);
                *(unsigned*)&H8[(size_t)row * HDIM + lr * 8 + wn * 4] = pk;
            }
        }
    }
}

// ---------------- output GEMM + fused bias + log_softmax ----------------

__global__ __launch_bounds__(256) void k_gemm_out(
    const ushort* __restrict__ A, const ushort* __restrict__ W,
    const float* __restrict__ bias, float* __restrict__ out) {
    const int tid = threadIdx.x;
    const int wid = tid >> 6, l = tid & 63;
    const int lr = l & 15, lk = l >> 4;
    const int row0 = blockIdx.x * 128 + wid * 32;

    short8 a[2][4], b[4][4];
#pragma unroll
    for (int m = 0; m < 2; ++m)
#pragma unroll
        for (int k = 0; k < 4; ++k)
            a[m][k] = *(const short8*)&A[(size_t)(row0 + m * 16 + lr) * HDIM + k * 32 + lk * 8];
#pragma unroll
    for (int n = 0; n < 4; ++n)
#pragma unroll
        for (int k = 0; k < 4; ++k)
            b[n][k] = *(const short8*)&W[(size_t)(n * 16 + lr) * HDIM + k * 32 + lk * 8];

    f32x4 acc[2][4];
#pragma unroll
    for (int m = 0; m < 2; ++m)
#pragma unroll
        for (int n = 0; n < 4; ++n) acc[m][n] = (f32x4){0.f, 0.f, 0.f, 0.f};
#pragma unroll
    for (int k = 0; k < 4; ++k)
#pragma unroll
        for (int m = 0; m < 2; ++m)
#pragma unroll
            for (int n = 0; n < 4; ++n)
                acc[m][n] = __builtin_amdgcn_mfma_f32_16x16x32_bf16(a[m][k], b[n][k], acc[m][n], 0, 0, 0);

    float bv[4];
#pragma unroll
    for (int n = 0; n < 4; ++n) bv[n] = bias[n * 16 + lr];

#pragma unroll
    for (int m = 0; m < 2; ++m) {
#pragma unroll
        for (int j = 0; j < 4; ++j) {
            float z[4];
#pragma unroll
            for (int n = 0; n < 4; ++n) z[n] = acc[m][n][j] + bv[n];
            float mx = fmaxf(fmaxf(z[0], z[1]), fmaxf(z[2], z[3]));
#pragma unroll
            for (int off = 1; off < 16; off <<= 1) mx = fmaxf(mx, __shfl_xor(mx, off));
            float s = 0.f;
#pragma unroll
            for (int n = 0; n < 4; ++n) s += expf(z[n] - mx);
#pragma unroll
            for (int off = 1; off < 16; off <<= 1) s += __shfl_xor(s, off);
            float lg = mx + logf(s);
            int r = row0 + m * 16 + lk * 4 + j;
            if (r < N_NODES) {
#pragma unroll
                for (int n = 0; n < 4; ++n)
                    out[(size_t)r * COUT + n * 16 + lr] = z[n] - lg;
            }
        }
    }
}

// ---------------- launch ----------------

extern "C" void kernel_launch(void* const* d_in, const int* in_sizes, int n_in,
                              void* d_out, int out_size, void* d_ws, size_t ws_size,
                              hipStream_t stream) {
    const float* x = (const float*)d_in[0];
    const int* ei = (const int*)d_in[1];
    const float* ew = (const float*)d_in[2];
    const float* w_in = (const float*)d_in[3];
    const float* b_in = (const float*)d_in[4];
    const float* ws1 = (const float*)d_in[5];
    const float* ws2 = (const float*)d_in[6];
    const float* w_out = (const float*)d_in[7];
    const float* b_out = (const float*)d_in[8];
    float* out = (float*)d_out;

    char* p = (char*)d_ws;
    auto alloc = [&](size_t bytes) {
        void* r = (void*)p;
        p += (bytes + 255) & ~(size_t)255;
        return r;
    };
    float* dinv = (float*)alloc(N_NODES * 4);     // deg -> dinv in place
    int* cnt = (int*)alloc(N_NODES * 4);
    int* ptrTmp = (int*)alloc(N_NODES * 4);
    int* bsum = (int*)alloc(256 * 4);
    int* boff = (int*)alloc(256 * 4);
    int* ptr = (int*)alloc((N_NODES + 1) * 4);
    int* rank = (int*)alloc((size_t)E_EDGES * 4);
    unsigned* spacku = (unsigned*)alloc((size_t)E_EDGES * 4);
    ushort* xb = (ushort*)alloc((size_t)N_PAD * HDIM * 2);
    ushort* h = (ushort*)alloc((size_t)N_PAD * HDIM * 2);
    ushort* h0 = (ushort*)alloc((size_t)N_PAD * HDIM * 2);
    ushort* agg_h = (ushort*)alloc((size_t)N_PAD * HDIM * 2);
    unsigned char* h8 = (unsigned char*)alloc((size_t)N_PAD * HDIM);
    ushort* wt_in = (ushort*)alloc(128 * 128 * 2);
    ushort* wt1 = (ushort*)alloc((size_t)NLAYERS * 128 * 128 * 2);
    ushort* wt2 = (ushort*)alloc((size_t)NLAYERS * 128 * 128 * 2);
    ushort* wt_out = (ushort*)alloc(64 * 128 * 2);

    const int ge4 = (E_EDGES / 4 + 255) / 256;  // 625
    k_init<<<SCAN_BLKS, 256, 0, stream>>>(dinv, cnt);
    k_edge<<<ge4, 256, 0, stream>>>(ei, ew, dinv, cnt, rank);
    k_dinv<<<SCAN_BLKS, 256, 0, stream>>>(dinv);
    k_scan1<<<SCAN_BLKS, 256, 0, stream>>>(cnt, ptrTmp, bsum);
    k_scan2<<<1, 256, 0, stream>>>(bsum, boff);
    k_scan3<<<SCAN_BLKS, 256, 0, stream>>>(ptrTmp, boff, ptr);
    k_scatter<<<ge4, 256, 0, stream>>>(ei, ew, dinv, ptr, rank, spacku);

    k_convert_w<<<34, 256, 0, stream>>>(w_in, ws1, ws2, w_out, wt_in, wt1, wt2, wt_out);
    k_convert_x<<<(N_PAD * (HDIM / 8) + 255) / 256, 256, 0, stream>>>(x, xb);

    const int gb = N_PAD / 128;  // 391
    k_gemm_in<<<gb, 256, 0, stream>>>(xb, wt_in, b_in, h0, h8);

    for (int i = 0; i < NLAYERS; ++i) {
        k_aggregate<<<(N_NODES + 3) / 4, 256, 0, stream>>>(h8, dinv, ptr, spacku, agg_h);
        if (i < NLAYERS - 1)
            k_gemm_layer<false><<<gb, 256, 0, stream>>>(agg_h, h0,
                                                        wt1 + (size_t)i * 16384,
                                                        wt2 + (size_t)i * 16384, h, h8);
        else
            k_gemm_layer<true><<<gb, 256, 0, stream>>>(agg_h, h0,
                                                       wt1 + (size_t)i * 16384,
                                                       wt2 + (size_t)i * 16384, h, h8);
    }

    k_gemm_out<<<gb, 256, 0, stream>>>(h, wt_out, b_out, out);
}

// Round 17
// 701.927 us; speedup vs baseline: 1.0181x; 1.0181x over previous
//
#include <hip/hip_runtime.h>
#include <cmath>
#include <cstddef>

#define N_NODES 50000
#define N_PAD   50048
#define E_EDGES 640000
#define HDIM 128
#define COUT 64
#define NLAYERS 16
#define ALPHA_C 0.1f
#define LAMDA_C 0.5f
#define SCAN_BLKS 196   // ceil(50000/256)

typedef __attribute__((ext_vector_type(8))) short short8;
typedef __attribute__((ext_vector_type(4))) float f32x4;
typedef __attribute__((ext_vector_type(2))) float f32x2;
typedef __attribute__((address_space(1))) const unsigned int g_u32;
typedef __attribute__((address_space(3))) unsigned int l_u32;

__device__ __forceinline__ float bf2f(ushort u) {
    union { unsigned u; float f; } x; x.u = ((unsigned)u) << 16; return x.f;
}
__device__ __forceinline__ ushort f2bf(float f) {
    union { float f; unsigned u; } x; x.f = f;
    unsigned r = x.u + 0x7FFFu + ((x.u >> 16) & 1u);
    return (ushort)(r >> 16);
}

// ---------------- graph setup ----------------

__global__ __launch_bounds__(256) void k_init(float* deg, int* cnt) {
    int i = blockIdx.x * 256 + threadIdx.x;
    if (i < N_NODES) { deg[i] = 1.0f; cnt[i] = 0; }
}

// 4 edges/thread; cnt atomicAdd return value = intra-bucket rank (kills scatter atomics)
__global__ __launch_bounds__(256) void k_edge(const int* __restrict__ ei,
                                              const float* __restrict__ ew,
                                              float* deg, int* cnt,
                                              int* __restrict__ rank) {
    int t = blockIdx.x * 256 + threadIdx.x;
    int e0 = t * 4;
    if (e0 >= E_EDGES) return;
    int4 r = *(const int4*)&ei[e0];
    int4 c = *(const int4*)&ei[E_EDGES + e0];
    float4 w = *(const float4*)&ew[e0];
    atomicAdd(&deg[r.x], w.x);
    atomicAdd(&deg[r.y], w.y);
    atomicAdd(&deg[r.z], w.z);
    atomicAdd(&deg[r.w], w.w);
    int4 rk;
    rk.x = atomicAdd(&cnt[c.x], 1);
    rk.y = atomicAdd(&cnt[c.y], 1);
    rk.z = atomicAdd(&cnt[c.z], 1);
    rk.w = atomicAdd(&cnt[c.w], 1);
    *(int4*)&rank[e0] = rk;
}

__global__ __launch_bounds__(256) void k_dinv(float* deg) {
    int i = blockIdx.x * 256 + threadIdx.x;
    if (i < N_NODES) deg[i] = 1.0f / sqrtf(deg[i]);
}

__global__ __launch_bounds__(256) void k_scan1(const int* __restrict__ cnt,
                                               int* ptrTmp, int* bsum) {
    __shared__ int s[256];
    int t = threadIdx.x;
    int i = blockIdx.x * 256 + t;
    int v = (i < N_NODES) ? cnt[i] : 0;
    s[t] = v; __syncthreads();
    for (int off = 1; off < 256; off <<= 1) {
        int x = s[t]; int y = (t >= off) ? s[t - off] : 0;
        __syncthreads();
        s[t] = x + y; __syncthreads();
    }
    if (i < N_NODES) ptrTmp[i] = s[t] - v;
    if (t == 255) bsum[blockIdx.x] = s[255];
}

__global__ __launch_bounds__(256) void k_scan2(const int* __restrict__ bsum, int* boff) {
    __shared__ int s[256];
    int t = threadIdx.x;
    int v = (t < SCAN_BLKS) ? bsum[t] : 0;
    s[t] = v; __syncthreads();
    for (int off = 1; off < 256; off <<= 1) {
        int x = s[t]; int y = (t >= off) ? s[t - off] : 0;
        __syncthreads();
        s[t] = x + y; __syncthreads();
    }
    if (t < SCAN_BLKS) boff[t] = s[t] - v;
}

__global__ __launch_bounds__(256) void k_scan3(const int* __restrict__ ptrTmp,
                                               const int* __restrict__ boff, int* ptr) {
    int i = blockIdx.x * 256 + threadIdx.x;
    if (i < N_NODES) ptr[i] = ptrTmp[i] + boff[blockIdx.x];
    if (i == 0) ptr[N_NODES] = E_EDGES;
}

// atomic-free scatter: pos = ptr[c] + rank[e]; meta packed (row<<16 | bf16(norm))
__global__ __launch_bounds__(256) void k_scatter(const int* __restrict__ ei,
                                                 const float* __restrict__ ew,
                                                 const float* __restrict__ dinv,
                                                 const int* __restrict__ ptr,
                                                 const int* __restrict__ rank,
                                                 unsigned* __restrict__ spacku) {
    int t = blockIdx.x * 256 + threadIdx.x;
    int e0 = t * 4;
    if (e0 >= E_EDGES) return;
    int4 r = *(const int4*)&ei[e0];
    int4 c = *(const int4*)&ei[E_EDGES + e0];
    float4 w = *(const float4*)&ew[e0];
    int4 rk = *(const int4*)&rank[e0];
#pragma unroll
    for (int j = 0; j < 4; ++j) {
        int rr = (j == 0) ? r.x : (j == 1) ? r.y : (j == 2) ? r.z : r.w;
        int cc = (j == 0) ? c.x : (j == 1) ? c.y : (j == 2) ? c.z : c.w;
        float wwv = (j == 0) ? w.x : (j == 1) ? w.y : (j == 2) ? w.z : w.w;
        int rkj = (j == 0) ? rk.x : (j == 1) ? rk.y : (j == 2) ? rk.z : rk.w;
        int pos = ptr[cc] + rkj;
        float nm = dinv[rr] * wwv * dinv[cc];
        spacku[pos] = ((unsigned)rr << 16) | (unsigned)f2bf(nm);
    }
}

// ---------------- weight convert + transpose + residual fold ----------------
// layer weights become W' = beta*W + diagC*I, stored bf16 transposed [C][R]

__global__ __launch_bounds__(256) void k_convert_w(
    const float* __restrict__ w_in, const float* __restrict__ ws1,
    const float* __restrict__ ws2, const float* __restrict__ w_out,
    ushort* wt_in, ushort* wt1, ushort* wt2, ushort* wt_out) {
    __shared__ float tile[128][129];
    int b = blockIdx.x;
    const float* src; ushort* dst; int R = 128, C = 128;
    float scale = 1.f, diag = 0.f;
    if (b == 0) { src = w_in; dst = wt_in; }
    else if (b <= 16) {
        int i = b - 1;
        float beta = logf(LAMDA_C / (float)(i + 1) + 1.0f);
        scale = beta; diag = (1.f - beta) * (1.f - ALPHA_C);
        src = ws1 + (size_t)i * 16384; dst = wt1 + (size_t)i * 16384;
    } else if (b <= 32) {
        int i = b - 17;
        float beta = logf(LAMDA_C / (float)(i + 1) + 1.0f);
        scale = beta; diag = (1.f - beta) * ALPHA_C;
        src = ws2 + (size_t)i * 16384; dst = wt2 + (size_t)i * 16384;
    } else { src = w_out; dst = wt_out; C = 64; }
    for (int idx = threadIdx.x; idx < R * C; idx += 256) {
        int k = idx / C, n = idx % C;
        tile[k][n] = src[idx] * scale + ((k == n) ? diag : 0.f);
    }
    __syncthreads();
    for (int idx = threadIdx.x; idx < R * C; idx += 256) {
        int n = idx / R, k = idx % R;
        dst[idx] = f2bf(tile[k][n]);
    }
}

// ---------------- x convert (f32 -> bf16, zero-pad rows) ----------------

__global__ __launch_bounds__(256) void k_convert_x(const float* __restrict__ x,
                                                   ushort* __restrict__ xb) {
    int c8 = blockIdx.x * 256 + threadIdx.x;
    if (c8 >= N_PAD * (HDIM / 8)) return;
    int row = c8 / (HDIM / 8);
    short8 o;
    if (row < N_NODES) {
        const float4 f0 = *(const float4*)&x[(size_t)c8 * 8];
        const float4 f1 = *(const float4*)&x[(size_t)c8 * 8 + 4];
        o[0] = (short)f2bf(f0.x); o[1] = (short)f2bf(f0.y);
        o[2] = (short)f2bf(f0.z); o[3] = (short)f2bf(f0.w);
        o[4] = (short)f2bf(f1.x); o[5] = (short)f2bf(f1.y);
        o[6] = (short)f2bf(f1.z); o[7] = (short)f2bf(f1.w);
    } else {
        o = (short8){0, 0, 0, 0, 0, 0, 0, 0};
    }
    *(short8*)&xb[(size_t)c8 * 8] = o;
}

// ---------------- input GEMM: h0 = relu(xb @ W + bias); also h8 (fp8 perm) ----------------
// h8 byte pdim=(dim&15)*8+(dim>>4).

__global__ __launch_bounds__(256) void k_gemm_in(
    const ushort* __restrict__ A, const ushort* __restrict__ W,
    const float* __restrict__ bias, ushort* __restrict__ H0,
    unsigned char* __restrict__ H8) {
    const int tid = threadIdx.x;
    const int wid = tid >> 6, l = tid & 63;
    const int wm = wid >> 1, wn = wid & 1;
    const int lr = l & 15, lk = l >> 4;
    const int row0 = blockIdx.x * 128 + wm * 64;
    const int col0 = wn * 64;

    short8 a[4][4], b[4][4];
#pragma unroll
    for (int m = 0; m < 4; ++m)
#pragma unroll
        for (int k = 0; k < 4; ++k)
            a[m][k] = *(const short8*)&A[(size_t)(row0 + m * 16 + lr) * HDIM + k * 32 + lk * 8];
#pragma unroll
    for (int n = 0; n < 4; ++n)
#pragma unroll
        for (int k = 0; k < 4; ++k)
            b[n][k] = *(const short8*)&W[(size_t)(col0 + n * 16 + lr) * HDIM + k * 32 + lk * 8];

    f32x4 acc[4][4];
#pragma unroll
    for (int m = 0; m < 4; ++m)
#pragma unroll
        for (int n = 0; n < 4; ++n) acc[m][n] = (f32x4){0.f, 0.f, 0.f, 0.f};
#pragma unroll
    for (int k = 0; k < 4; ++k)
#pragma unroll
        for (int m = 0; m < 4; ++m)
#pragma unroll
            for (int n = 0; n < 4; ++n)
                acc[m][n] = __builtin_amdgcn_mfma_f32_16x16x32_bf16(a[m][k], b[n][k], acc[m][n], 0, 0, 0);

    float bv[4];
#pragma unroll
    for (int n = 0; n < 4; ++n) bv[n] = bias[col0 + n * 16 + lr];
#pragma unroll
    for (int m = 0; m < 4; ++m) {
        const int rb = row0 + m * 16 + lk * 4;
#pragma unroll
        for (int j = 0; j < 4; ++j) {
            const int row = rb + j;
            const size_t ro = (size_t)row * HDIM;
            float v[4];
#pragma unroll
            for (int n = 0; n < 4; ++n) {
                v[n] = fmaxf(acc[m][n][j] + bv[n], 0.f);
                H0[ro + col0 + n * 16 + lr] = f2bf(v[n]);
            }
            unsigned pk = 0;
            pk = __builtin_amdgcn_cvt_pk_fp8_f32(v[0], v[1], pk, false);
            pk = __builtin_amdgcn_cvt_pk_fp8_f32(v[2], v[3], pk, true);
            *(unsigned*)&H8[(size_t)row * HDIM + lr * 8 + wn * 4] = pk;
        }
    }
}

// ---------------- aggregation: agg_h = A_hat * h  (fp8 gathers, 128B/edge) ----------------
// R13 shape: wave per node; quarter-wave (16 lanes x uint2 = 128B row) per edge;
// 16 edges in flight (4x unroll); branch-free (padded lanes carry meta=0).

__global__ __launch_bounds__(256) void k_aggregate(
    const unsigned char* __restrict__ h8, const float* __restrict__ dinv,
    const int* __restrict__ ptr, const unsigned* __restrict__ spacku,
    ushort* __restrict__ agg_h) {
    const int v = blockIdx.x * 4 + (threadIdx.x >> 6);
    const int l = threadIdx.x & 63;
    const int q = l >> 4, i = l & 15;
    if (v >= N_NODES) return;
    const int beg = ptr[v], end = ptr[v + 1];

    float acc[8];
#pragma unroll
    for (int d = 0; d < 8; ++d) acc[d] = 0.f;

    for (int base = beg; base < end; base += 64) {
        const int cnt = min(64, end - base);
        unsigned meta = 0;
        if (base + l < end) meta = spacku[base + l];
        for (int j = 0; j < cnt; j += 16) {
            unsigned mu0 = (unsigned)__shfl((int)meta, j + q);
            unsigned mu1 = (unsigned)__shfl((int)meta, j + 4 + q);
            unsigned mu2 = (unsigned)__shfl((int)meta, j + 8 + q);
            unsigned mu3 = (unsigned)__shfl((int)meta, j + 12 + q);
            uint2 u0 = *(const uint2*)&h8[(size_t)(mu0 >> 16) * HDIM + i * 8];
            uint2 u1 = *(const uint2*)&h8[(size_t)(mu1 >> 16) * HDIM + i * 8];
            uint2 u2 = *(const uint2*)&h8[(size_t)(mu2 >> 16) * HDIM + i * 8];
            uint2 u3 = *(const uint2*)&h8[(size_t)(mu3 >> 16) * HDIM + i * 8];
            float nn0 = bf2f((ushort)(mu0 & 0xFFFFu));
            float nn1 = bf2f((ushort)(mu1 & 0xFFFFu));
            float nn2 = bf2f((ushort)(mu2 & 0xFFFFu));
            float nn3 = bf2f((ushort)(mu3 & 0xFFFFu));
#pragma unroll
            for (int e = 0; e < 4; ++e) {
                uint2 u = (e == 0) ? u0 : (e == 1) ? u1 : (e == 2) ? u2 : u3;
                float nn = (e == 0) ? nn0 : (e == 1) ? nn1 : (e == 2) ? nn2 : nn3;
                f32x2 f0 = __builtin_amdgcn_cvt_pk_f32_fp8(u.x, false);
                f32x2 f1 = __builtin_amdgcn_cvt_pk_f32_fp8(u.x, true);
                f32x2 f2 = __builtin_amdgcn_cvt_pk_f32_fp8(u.y, false);
                f32x2 f3 = __builtin_amdgcn_cvt_pk_f32_fp8(u.y, true);
                acc[0] = fmaf(nn, f0.x, acc[0]);
                acc[1] = fmaf(nn, f0.y, acc[1]);
                acc[2] = fmaf(nn, f1.x, acc[2]);
                acc[3] = fmaf(nn, f1.y, acc[3]);
                acc[4] = fmaf(nn, f2.x, acc[4]);
                acc[5] = fmaf(nn, f2.y, acc[5]);
                acc[6] = fmaf(nn, f3.x, acc[6]);
                acc[7] = fmaf(nn, f3.y, acc[7]);
            }
        }
    }
#pragma unroll
    for (int d = 0; d < 8; ++d) {
        acc[d] += __shfl_xor(acc[d], 16);
        acc[d] += __shfl_xor(acc[d], 32);
    }
    if (q == 0) {
        const float dv = dinv[v];
        const float dv2 = dv * dv;
        uint2 u = *(const uint2*)&h8[(size_t)v * HDIM + i * 8];
        f32x2 f0 = __builtin_amdgcn_cvt_pk_f32_fp8(u.x, false);
        f32x2 f1 = __builtin_amdgcn_cvt_pk_f32_fp8(u.x, true);
        f32x2 f2 = __builtin_amdgcn_cvt_pk_f32_fp8(u.y, false);
        f32x2 f3 = __builtin_amdgcn_cvt_pk_f32_fp8(u.y, true);
        float s[8] = {f0.x, f0.y, f1.x, f1.y, f2.x, f2.y, f3.x, f3.y};
#pragma unroll
        for (int n = 0; n < 8; ++n)
            agg_h[(size_t)v * HDIM + n * 16 + i] = f2bf(acc[n] + dv2 * s[n]);
    }
}

// ---------------- layer GEMM: h = relu(agg_h @ W1' + h0 @ W2') ----------------
// R15 config (best): A-tiles staged into 32KB LDS via global_load_lds (width 16),
// XOR-swizzled source (granule g^(row&7)) so linear LDS + swizzled ds_read_b128
// is conflict-free. One buffer, two phases (AGG then W1; H0 then W2).
// 3 blocks/CU — other blocks' compute covers each block's stage latency
// (R16 proved the 64KB single-barrier variant is worse: occupancy 3->2).
// LAST=false: write only H8 (fp8). LAST=true (layer 15): write only H (bf16).

template <bool LAST>
__global__ __launch_bounds__(256, 3) void k_gemm_layer(
    const ushort* __restrict__ AGG, const ushort* __restrict__ H0,
    const ushort* __restrict__ W1, const ushort* __restrict__ W2,
    ushort* __restrict__ H, unsigned char* __restrict__ H8) {
    __shared__ ushort ldsA[128 * 128];   // 32 KB
    const int tid = threadIdx.x;
    const int wid = tid >> 6, l = tid & 63;
    const int wm = wid >> 1, wn = wid & 1;
    const int lr = l & 15, lk = l >> 4;
    const int tilebase = blockIdx.x * 128;
    const int col0 = wn * 64;

    f32x4 acc[4][4];
#pragma unroll
    for (int m = 0; m < 4; ++m)
#pragma unroll
        for (int n = 0; n < 4; ++n) acc[m][n] = (f32x4){0.f, 0.f, 0.f, 0.f};

#pragma unroll
    for (int ph = 0; ph < 2; ++ph) {
        const ushort* __restrict__ A = ph ? H0 : AGG;
        const ushort* __restrict__ W = ph ? W2 : W1;
        if (ph) __syncthreads();   // all waves done reading phase-0 LDS
        // stage 128x128 bf16 tile: 8 rounds x (4 waves x 64 lanes x 16B)
#pragma unroll
        for (int r = 0; r < 8; ++r) {
            int p = (r * 4 + wid) * 64 + l;       // granule 0..2047
            int row = p >> 4, g = p & 15;
            int gs = g ^ (row & 7);
            __builtin_amdgcn_global_load_lds(
                (g_u32*)(A + (size_t)(tilebase + row) * HDIM + gs * 8),
                (l_u32*)&ldsA[(size_t)p * 8], 16, 0, 0);
        }
        __syncthreads();
#pragma unroll
        for (int k = 0; k < 4; ++k) {
            short8 a[4], b[4];
#pragma unroll
            for (int m = 0; m < 4; ++m) {
                int rloc = wm * 64 + m * 16 + lr;
                int gs = (k * 4 + lk) ^ (rloc & 7);
                a[m] = *(const short8*)&ldsA[rloc * 128 + gs * 8];
            }
#pragma unroll
            for (int n = 0; n < 4; ++n)
                b[n] = *(const short8*)&W[(size_t)(col0 + n * 16 + lr) * HDIM + k * 32 + lk * 8];
#pragma unroll
            for (int m = 0; m < 4; ++m)
#pragma unroll
                for (int n = 0; n < 4; ++n)
                    acc[m][n] = __builtin_amdgcn_mfma_f32_16x16x32_bf16(a[m], b[n], acc[m][n], 0, 0, 0);
        }
    }

#pragma unroll
    for (int m = 0; m < 4; ++m) {
        const int rb = tilebase + wm * 64 + m * 16 + lk * 4;
#pragma unroll
        for (int j = 0; j < 4; ++j) {
            const int row = rb + j;
            const size_t ro = (size_t)row * HDIM;
            float v[4];
#pragma unroll
            for (int n = 0; n < 4; ++n) v[n] = fmaxf(acc[m][n][j], 0.f);
            if constexpr (LAST) {
#pragma unroll
                for (int n = 0; n < 4; ++n)
                    H[ro + col0 + n * 16 + lr] = f2bf(v[n]);
            } else {
                unsigned pk = 0;
                pk = __builtin_amdgcn_cvt_pk_fp8_f32(v[0], v[1], pk, false);
                pk = __builtin_amdgcn_cvt_pk_fp8_f32(v[2], v[3], pk, true);
                *(unsigned*)&H8[(size_t)row * HDIM + lr * 8 + wn * 4] = pk;
            }
        }
    }
}

// ---------------- output GEMM + fused bias + log_softmax ----------------

__global__ __launch_bounds__(256) void k_gemm_out(
    const ushort* __restrict__ A, const ushort* __restrict__ W,
    const float* __restrict__ bias, float* __restrict__ out) {
    const int tid = threadIdx.x;
    const int wid = tid >> 6, l = tid & 63;
    const int lr = l & 15, lk = l >> 4;
    const int row0 = blockIdx.x * 128 + wid * 32;

    short8 a[2][4], b[4][4];
#pragma unroll
    for (int m = 0; m < 2; ++m)
#pragma unroll
        for (int k = 0; k < 4; ++k)
            a[m][k] = *(const short8*)&A[(size_t)(row0 + m * 16 + lr) * HDIM + k * 32 + lk * 8];
#pragma unroll
    for (int n = 0; n < 4; ++n)
#pragma unroll
        for (int k = 0; k < 4; ++k)
            b[n][k] = *(const short8*)&W[(size_t)(n * 16 + lr) * HDIM + k * 32 + lk * 8];

    f32x4 acc[2][4];
#pragma unroll
    for (int m = 0; m < 2; ++m)
#pragma unroll
        for (int n = 0; n < 4; ++n) acc[m][n] = (f32x4){0.f, 0.f, 0.f, 0.f};
#pragma unroll
    for (int k = 0; k < 4; ++k)
#pragma unroll
        for (int m = 0; m < 2; ++m)
#pragma unroll
            for (int n = 0; n < 4; ++n)
                acc[m][n] = __builtin_amdgcn_mfma_f32_16x16x32_bf16(a[m][k], b[n][k], acc[m][n], 0, 0, 0);

    float bv[4];
#pragma unroll
    for (int n = 0; n < 4; ++n) bv[n] = bias[n * 16 + lr];

#pragma unroll
    for (int m = 0; m < 2; ++m) {
#pragma unroll
        for (int j = 0; j < 4; ++j) {
            float z[4];
#pragma unroll
            for (int n = 0; n < 4; ++n) z[n] = acc[m][n][j] + bv[n];
            float mx = fmaxf(fmaxf(z[0], z[1]), fmaxf(z[2], z[3]));
#pragma unroll
            for (int off = 1; off < 16; off <<= 1) mx = fmaxf(mx, __shfl_xor(mx, off));
            float s = 0.f;
#pragma unroll
            for (int n = 0; n < 4; ++n) s += expf(z[n] - mx);
#pragma unroll
            for (int off = 1; off < 16; off <<= 1) s += __shfl_xor(s, off);
            float lg = mx + logf(s);
            int r = row0 + m * 16 + lk * 4 + j;
            if (r < N_NODES) {
#pragma unroll
                for (int n = 0; n < 4; ++n)
                    out[(size_t)r * COUT + n * 16 + lr] = z[n] - lg;
            }
        }
    }
}

// ---------------- launch ----------------

extern "C" void kernel_launch(void* const* d_in, const int* in_sizes, int n_in,
                              void* d_out, int out_size, void* d_ws, size_t ws_size,
                              hipStream_t stream) {
    const float* x = (const float*)d_in[0];
    const int* ei = (const int*)d_in[1];
    const float* ew = (const float*)d_in[2];
    const float* w_in = (const float*)d_in[3];
    const float* b_in = (const float*)d_in[4];
    const float* ws1 = (const float*)d_in[5];
    const float* ws2 = (const float*)d_in[6];
    const float* w_out = (const float*)d_in[7];
    const float* b_out = (const float*)d_in[8];
    float* out = (float*)d_out;

    char* p = (char*)d_ws;
    auto alloc = [&](size_t bytes) {
        void* r = (void*)p;
        p += (bytes + 255) & ~(size_t)255;
        return r;
    };
    float* dinv = (float*)alloc(N_NODES * 4);     // deg -> dinv in place
    int* cnt = (int*)alloc(N_NODES * 4);
    int* ptrTmp = (int*)alloc(N_NODES * 4);
    int* bsum = (int*)alloc(256 * 4);
    int* boff = (int*)alloc(256 * 4);
    int* ptr = (int*)alloc((N_NODES + 1) * 4);
    int* rank = (int*)alloc((size_t)E_EDGES * 4);
    unsigned* spacku = (unsigned*)alloc((size_t)E_EDGES * 4);
    ushort* xb = (ushort*)alloc((size_t)N_PAD * HDIM * 2);
    ushort* h = (ushort*)alloc((size_t)N_PAD * HDIM * 2);
    ushort* h0 = (ushort*)alloc((size_t)N_PAD * HDIM * 2);
    ushort* agg_h = (ushort*)alloc((size_t)N_PAD * HDIM * 2);
    unsigned char* h8 = (unsigned char*)alloc((size_t)N_PAD * HDIM);
    ushort* wt_in = (ushort*)alloc(128 * 128 * 2);
    ushort* wt1 = (ushort*)alloc((size_t)NLAYERS * 128 * 128 * 2);
    ushort* wt2 = (ushort*)alloc((size_t)NLAYERS * 128 * 128 * 2);
    ushort* wt_out = (ushort*)alloc(64 * 128 * 2);

    const int ge4 = (E_EDGES / 4 + 255) / 256;  // 625
    k_init<<<SCAN_BLKS, 256, 0, stream>>>(dinv, cnt);
    k_edge<<<ge4, 256, 0, stream>>>(ei, ew, dinv, cnt, rank);
    k_dinv<<<SCAN_BLKS, 256, 0, stream>>>(dinv);
    k_scan1<<<SCAN_BLKS, 256, 0, stream>>>(cnt, ptrTmp, bsum);
    k_scan2<<<1, 256, 0, stream>>>(bsum, boff);
    k_scan3<<<SCAN_BLKS, 256, 0, stream>>>(ptrTmp, boff, ptr);
    k_scatter<<<ge4, 256, 0, stream>>>(ei, ew, dinv, ptr, rank, spacku);

    k_convert_w<<<34, 256, 0, stream>>>(w_in, ws1, ws2, w_out, wt_in, wt1, wt2, wt_out);
    k_convert_x<<<(N_PAD * (HDIM / 8) + 255) / 256, 256, 0, stream>>>(x, xb);

    const int gb = N_PAD / 128;  // 391
    k_gemm_in<<<gb, 256, 0, stream>>>(xb, wt_in, b_in, h0, h8);

    for (int i = 0; i < NLAYERS; ++i) {
        k_aggregate<<<(N_NODES + 3) / 4, 256, 0, stream>>>(h8, dinv, ptr, spacku, agg_h);
        if (i < NLAYERS - 1)
            k_gemm_layer<false><<<gb, 256, 0, stream>>>(agg_h, h0,
                                                        wt1 + (size_t)i * 16384,
                                                        wt2 + (size_t)i * 16384, h, h8);
        else
            k_gemm_layer<true><<<gb, 256, 0, stream>>>(agg_h, h0,
                                                       wt1 + (size_t)i * 16384,
                                                       wt2 + (size_t)i * 16384, h, h8);
    }

    k_gemm_out<<<gb, 256, 0, stream>>>(h, wt_out, b_out, out);
}